// Round 7
// baseline (543.803 us; speedup 1.0000x reference)
//
#include <hip/hip_runtime.h>
#include <hip/hip_bf16.h>

// RPN proposal: top-2000 -> decode/clip -> greedy NMS -> top-1000 proposals.
// Pipeline: init -> hist(2048 bins) -> threshold -> collect -> bitonic sort ->
//           decode -> IoU bitmask matrix -> serial NMS (1 wave) -> scatter out.

typedef unsigned int uint;
typedef unsigned long long ull;

#define PRE_NMS   2000
#define POST_NMS  1000
#define SORT_N    4096
#define NBINS     2048
#define NMS_TH    0.7f
#define MIN_SIZE  1.0f
#define BBOX_CLIP 4.135166556742356f   // float(ln(1000/16))

// ---- ws layout (bytes) ----
#define HIST_OFF    0        // 2048 * 4 = 8192
#define META_OFF    8192     // 64 uints (meta[0]=threshold bin, meta[1]=cand count)
#define VALID_OFF   8448     // 32 * 8 = 256
#define CAND_OFF    8704     // 4096 * 8 = 32768
#define TOPIDX_OFF  41472    // 2000 * 4 = 8000
#define BOXES_OFF   49472    // 2000 * 16 = 32000 (16B aligned)
#define MASK_OFF    81472    // 2000 * 32 * 8 = 512000
#define REM_OFF     593472   // 32 * 8 = 256
#define ZERO_WORDS  2176     // (hist + meta + validWords) / 4 = 8704 B

__device__ __forceinline__ uint map_f32(float f) {
    uint u = __float_as_uint(f);
    return u ^ ((u & 0x80000000u) ? 0xFFFFFFFFu : 0x80000000u);
}

// ---------------- 0. zero ws header + output --------------------------------
__global__ __launch_bounds__(256) void init_kernel(uint* __restrict__ wsHead,
                                                   float4* __restrict__ out) {
    int t = blockIdx.x * 256 + threadIdx.x;
    if (t < ZERO_WORDS) wsHead[t] = 0u;
    if (t < POST_NMS) out[t] = make_float4(0.f, 0.f, 0.f, 0.f);
}

// ---------------- 1. histogram of top 11 bits of mapped score ----------------
__global__ __launch_bounds__(256) void hist_kernel(const float* __restrict__ obj,
                                                   int n, uint* __restrict__ hist) {
    __shared__ uint h[NBINS];
    for (int b = threadIdx.x; b < NBINS; b += 256) h[b] = 0;
    __syncthreads();
    int n4 = n >> 2;
    const float4* obj4 = reinterpret_cast<const float4*>(obj);
    int stride = gridDim.x * blockDim.x;
    for (int i = blockIdx.x * blockDim.x + threadIdx.x; i < n4; i += stride) {
        float4 v = obj4[i];
        atomicAdd(&h[map_f32(v.x) >> 21], 1u);
        atomicAdd(&h[map_f32(v.y) >> 21], 1u);
        atomicAdd(&h[map_f32(v.z) >> 21], 1u);
        atomicAdd(&h[map_f32(v.w) >> 21], 1u);
    }
    // tail
    int base = n4 << 2;
    for (int i = base + blockIdx.x * blockDim.x + threadIdx.x; i < n; i += stride)
        atomicAdd(&h[map_f32(obj[i]) >> 21], 1u);
    __syncthreads();
    for (int b = threadIdx.x; b < NBINS; b += 256)
        if (h[b]) atomicAdd(&hist[b], h[b]);
}

// ---------------- 2. find threshold bin (cum-from-top crosses PRE_NMS) -------
__global__ __launch_bounds__(256) void thresh_kernel(const uint* __restrict__ hist,
                                                     uint* __restrict__ meta) {
    __shared__ uint s_sum[256];
    __shared__ uint s_suf[256];
    int t = threadIdx.x;
    uint local[8];
    uint sum = 0;
#pragma unroll 8
    for (int b = 0; b < 8; b++) { local[b] = hist[t * 8 + b]; sum += local[b]; }
    s_sum[t] = sum;
    __syncthreads();
    if (t == 0) {
        uint acc = 0;
        for (int c = 255; c >= 0; c--) { s_suf[c] = acc; acc += s_sum[c]; }
    }
    __syncthreads();
    uint c = s_suf[t];  // count strictly above this chunk
#pragma unroll 8
    for (int b = 7; b >= 0; b--) {
        uint nc = c + local[b];
        if (c < (uint)PRE_NMS && nc >= (uint)PRE_NMS) meta[0] = (uint)(t * 8 + b);
        c = nc;
    }
}

// ---------------- 3. collect candidates >= threshold bin ---------------------
__global__ __launch_bounds__(256) void collect_kernel(const float* __restrict__ obj,
                                                      int n, uint* __restrict__ meta,
                                                      ull* __restrict__ cand) {
    uint T = meta[0];
    int n4 = n >> 2;
    const float4* obj4 = reinterpret_cast<const float4*>(obj);
    int stride = gridDim.x * blockDim.x;
    for (int i = blockIdx.x * blockDim.x + threadIdx.x; i < n4; i += stride) {
        float4 v = obj4[i];
        uint u0 = map_f32(v.x), u1 = map_f32(v.y), u2 = map_f32(v.z), u3 = map_f32(v.w);
        if ((u0 >> 21) >= T) {
            uint pos = atomicAdd(&meta[1], 1u);
            if (pos < (uint)SORT_N) cand[pos] = ((ull)u0 << 32) | (ull)(~(uint)(i * 4 + 0));
        }
        if ((u1 >> 21) >= T) {
            uint pos = atomicAdd(&meta[1], 1u);
            if (pos < (uint)SORT_N) cand[pos] = ((ull)u1 << 32) | (ull)(~(uint)(i * 4 + 1));
        }
        if ((u2 >> 21) >= T) {
            uint pos = atomicAdd(&meta[1], 1u);
            if (pos < (uint)SORT_N) cand[pos] = ((ull)u2 << 32) | (ull)(~(uint)(i * 4 + 2));
        }
        if ((u3 >> 21) >= T) {
            uint pos = atomicAdd(&meta[1], 1u);
            if (pos < (uint)SORT_N) cand[pos] = ((ull)u3 << 32) | (ull)(~(uint)(i * 4 + 3));
        }
    }
    int base = n4 << 2;
    for (int i = base + blockIdx.x * blockDim.x + threadIdx.x; i < n; i += stride) {
        uint u = map_f32(obj[i]);
        if ((u >> 21) >= T) {
            uint pos = atomicAdd(&meta[1], 1u);
            if (pos < (uint)SORT_N) cand[pos] = ((ull)u << 32) | (ull)(~(uint)i);
        }
    }
}

// ---------------- 4. bitonic sort (descending), emit top-2000 indices --------
__global__ __launch_bounds__(1024) void sort_kernel(const ull* __restrict__ cand,
                                                    const uint* __restrict__ meta,
                                                    int* __restrict__ topIdx) {
    __shared__ ull keys[SORT_N];
    uint n = meta[1]; if (n > (uint)SORT_N) n = SORT_N;
    for (int t = threadIdx.x; t < SORT_N; t += 1024)
        keys[t] = (t < (int)n) ? cand[t] : 0ULL;
    __syncthreads();
    for (int k = 2; k <= SORT_N; k <<= 1) {
        for (int j = k >> 1; j > 0; j >>= 1) {
            for (int t = threadIdx.x; t < SORT_N; t += 1024) {
                int ixj = t ^ j;
                if (ixj > t) {
                    ull A = keys[t], B = keys[ixj];
                    bool desc = ((t & k) == 0);
                    if (desc ? (A < B) : (A > B)) { keys[t] = B; keys[ixj] = A; }
                }
            }
            __syncthreads();
        }
    }
    for (int t = threadIdx.x; t < PRE_NMS; t += 1024)
        topIdx[t] = (int)(~(uint)keys[t]);   // low32 stored as ~idx
}

// ---------------- 5. gather + decode + clip + valid --------------------------
__global__ __launch_bounds__(256) void decode_kernel(const float* __restrict__ anchor,
                                                     const float* __restrict__ delta,
                                                     const int* __restrict__ topIdx,
                                                     const int* __restrict__ imh,
                                                     const int* __restrict__ imw,
                                                     float4* __restrict__ boxes,
                                                     ull* __restrict__ validWords) {
    int i = blockIdx.x * blockDim.x + threadIdx.x;
    if (i >= PRE_NMS) return;
    int idx = topIdx[i];
    const float4 a = reinterpret_cast<const float4*>(anchor)[idx];
    const float4 d = reinterpret_cast<const float4*>(delta)[idx];
    float W = (float)imw[0], H = (float)imh[0];
    float w  = a.z - a.x;
    float h  = a.w - a.y;
    float cx = a.x + 0.5f * w;
    float cy = a.y + 0.5f * h;
    float dw = fminf(d.z, BBOX_CLIP);
    float dh = fminf(d.w, BBOX_CLIP);
    float pcx = d.x * w + cx;
    float pcy = d.y * h + cy;
    float pw  = expf(dw) * w;
    float ph  = expf(dh) * h;
    float x1 = fminf(fmaxf(pcx - 0.5f * pw, 0.0f), W);
    float y1 = fminf(fmaxf(pcy - 0.5f * ph, 0.0f), H);
    float x2 = fminf(fmaxf(pcx + 0.5f * pw, 0.0f), W);
    float y2 = fminf(fmaxf(pcy + 0.5f * ph, 0.0f), H);
    boxes[i] = make_float4(x1, y1, x2, y2);
    bool valid = (x2 - x1 >= MIN_SIZE) && (y2 - y1 >= MIN_SIZE);
    if (valid) atomicOr(&validWords[i >> 6], 1ULL << (i & 63));
}

// ---------------- 6. suppression bitmatrix: mask[i][w] over j in [w*64, ...) -
__global__ __launch_bounds__(256) void mask_kernel(const float4* __restrict__ boxes,
                                                   ull* __restrict__ mask) {
    __shared__ float4 b[PRE_NMS];
    for (int t = threadIdx.x; t < PRE_NMS; t += 256) b[t] = boxes[t];
    __syncthreads();
    int tid = blockIdx.x * 256 + threadIdx.x;
    int i = tid >> 5, w = tid & 31;
    if (i >= PRE_NMS) return;
    float4 bi = b[i];
    float areai = (bi.z - bi.x) * (bi.w - bi.y);
    ull m = 0;
    int j0 = w * 64;
    for (int jj = 0; jj < 64; jj++) {
        int j = j0 + jj;
        if (j < PRE_NMS && j > i) {
            float4 bj = b[j];
            float xx1 = fmaxf(bi.x, bj.x), yy1 = fmaxf(bi.y, bj.y);
            float xx2 = fminf(bi.z, bj.z), yy2 = fminf(bi.w, bj.w);
            float inter = fmaxf(xx2 - xx1, 0.0f) * fmaxf(yy2 - yy1, 0.0f);
            float areaj = (bj.z - bj.x) * (bj.w - bj.y);
            float iou = inter / (areai + areaj - inter + 1e-9f);
            if (iou > NMS_TH) m |= (1ULL << jj);
        }
    }
    mask[i * 32 + w] = m;
}

// ---------------- 7. serial greedy NMS (one wave, 4-deep prefetch) -----------
__global__ __launch_bounds__(64) void nms_kernel(const ull* __restrict__ mask,
                                                 const ull* __restrict__ validWords,
                                                 ull* __restrict__ remOut) {
    int lane = threadIdx.x;
    ull rem = 0;
    if (lane < 32) rem = ~validWords[lane];   // removed = !valid
    auto LD = [&](int row) -> ull {
        return (lane < 32 && row < PRE_NMS) ? mask[row * 32 + lane] : 0ULL;
    };
    ull p0 = LD(0), p1 = LD(1), p2 = LD(2), p3 = LD(3);
    for (int i = 0; i < PRE_NMS; i += 4) {
        {
            ull rw = __shfl(rem, i >> 6);
            bool keep = !((rw >> (i & 63)) & 1ULL);
            ull row = p0; p0 = LD(i + 4);
            if (keep) rem |= row;
        }
        {
            ull rw = __shfl(rem, (i + 1) >> 6);
            bool keep = !((rw >> ((i + 1) & 63)) & 1ULL);
            ull row = p1; p1 = LD(i + 5);
            if (keep) rem |= row;
        }
        {
            ull rw = __shfl(rem, (i + 2) >> 6);
            bool keep = !((rw >> ((i + 2) & 63)) & 1ULL);
            ull row = p2; p2 = LD(i + 6);
            if (keep) rem |= row;
        }
        {
            ull rw = __shfl(rem, (i + 3) >> 6);
            bool keep = !((rw >> ((i + 3) & 63)) & 1ULL);
            ull row = p3; p3 = LD(i + 7);
            if (keep) rem |= row;
        }
    }
    if (lane < 32) remOut[lane] = rem;
}

// ---------------- 8. scatter kept boxes in positional (score) order ----------
__global__ __launch_bounds__(256) void output_kernel(const float4* __restrict__ boxes,
                                                     const ull* __restrict__ rem,
                                                     float4* __restrict__ out) {
    __shared__ uint pre[33];
    __shared__ ull kept_s[32];
    int t = threadIdx.x;
    if (t < 32) kept_s[t] = ~rem[t];
    __syncthreads();
    if (t == 0) {
        uint acc = 0;
        for (int w = 0; w < 32; w++) { pre[w] = acc; acc += (uint)__popcll(kept_s[w]); }
        pre[32] = acc;
    }
    __syncthreads();
    for (int i = t; i < PRE_NMS; i += 256) {
        ull kw = kept_s[i >> 6];
        if ((kw >> (i & 63)) & 1ULL) {
            uint rank = pre[i >> 6] +
                        (uint)__popcll(kw & ((1ULL << (i & 63)) - 1ULL));
            if (rank < (uint)POST_NMS) out[rank] = boxes[i];
        }
    }
}

extern "C" void kernel_launch(void* const* d_in, const int* in_sizes, int n_in,
                              void* d_out, int out_size, void* d_ws, size_t ws_size,
                              hipStream_t stream) {
    const float* anchor = (const float*)d_in[0];
    const float* obj    = (const float*)d_in[1];
    const float* delta  = (const float*)d_in[2];
    const int*   imh    = (const int*)d_in[3];
    const int*   imw    = (const int*)d_in[4];
    int n = in_sizes[1];

    char* ws = (char*)d_ws;
    uint* hist       = (uint*)(ws + HIST_OFF);
    uint* meta       = (uint*)(ws + META_OFF);
    ull*  validWords = (ull*)(ws + VALID_OFF);
    ull*  cand       = (ull*)(ws + CAND_OFF);
    int*  topIdx     = (int*)(ws + TOPIDX_OFF);
    float4* boxes    = (float4*)(ws + BOXES_OFF);
    ull*  mask       = (ull*)(ws + MASK_OFF);
    ull*  rem        = (ull*)(ws + REM_OFF);

    init_kernel<<<(ZERO_WORDS + 255) / 256, 256, 0, stream>>>(
        (uint*)ws, (float4*)d_out);
    hist_kernel<<<512, 256, 0, stream>>>(obj, n, hist);
    thresh_kernel<<<1, 256, 0, stream>>>(hist, meta);
    collect_kernel<<<512, 256, 0, stream>>>(obj, n, meta, cand);
    sort_kernel<<<1, 1024, 0, stream>>>(cand, meta, topIdx);
    decode_kernel<<<(PRE_NMS + 255) / 256, 256, 0, stream>>>(
        anchor, delta, topIdx, imh, imw, boxes, validWords);
    mask_kernel<<<(PRE_NMS * 32 + 255) / 256, 256, 0, stream>>>(boxes, mask);
    nms_kernel<<<1, 64, 0, stream>>>(mask, validWords, rem);
    output_kernel<<<1, 256, 0, stream>>>(boxes, rem, (float4*)d_out);
}

// Round 8
// 317.328 us; speedup vs baseline: 1.7137x; 1.7137x over previous
//
#include <hip/hip_runtime.h>
#include <hip/hip_bf16.h>

// RPN proposal: top-2000 -> decode/clip -> greedy NMS -> top-1000 proposals.
// Pipeline: init -> hist(2048 bins) -> threshold -> collect -> bitonic sort ->
//           decode -> IoU bitmask matrix -> blocked serial NMS -> scatter out.
//
// R7: nms_kernel rebuilt. Old version: 2000 serial steps each paying
// shfl (~50cyc) + load-latency/4 (~300cyc) = 380 cyc/step = 315 us (measured).
// New version: 32 blocks of 64 rows; remw replicated per-lane (1 shfl/block);
// whole 16KB mask blocks double-buffered into LDS via global_load_lds w=16
// with counted vmcnt(16); serial chain is pure VALU (~8 cyc/step).

typedef unsigned int uint;
typedef unsigned long long ull;

#define PRE_NMS   2000
#define POST_NMS  1000
#define SORT_N    4096
#define NBINS     2048
#define NMS_TH    0.7f
#define MIN_SIZE  1.0f
#define BBOX_CLIP 4.135166556742356f   // float(ln(1000/16))

// ---- ws layout (bytes) ----
#define HIST_OFF    0        // 2048 * 4 = 8192
#define META_OFF    8192     // 64 uints (meta[0]=threshold bin, meta[1]=cand count)
#define VALID_OFF   8448     // 32 * 8 = 256
#define CAND_OFF    8704     // 4096 * 8 = 32768
#define TOPIDX_OFF  41472    // 2000 * 4 = 8000
#define BOXES_OFF   49472    // 2000 * 16 = 32000 (16B aligned)
#define MASK_OFF    81472    // 2000 * 32 * 8 = 512000
#define REM_OFF     593472   // 32 * 8 = 256
#define ZERO_WORDS  2176     // (hist + meta + validWords) / 4 = 8704 B

__device__ __forceinline__ uint map_f32(float f) {
    uint u = __float_as_uint(f);
    return u ^ ((u & 0x80000000u) ? 0xFFFFFFFFu : 0x80000000u);
}

// ---------------- 0. zero ws header + output --------------------------------
__global__ __launch_bounds__(256) void init_kernel(uint* __restrict__ wsHead,
                                                   float4* __restrict__ out) {
    int t = blockIdx.x * 256 + threadIdx.x;
    if (t < ZERO_WORDS) wsHead[t] = 0u;
    if (t < POST_NMS) out[t] = make_float4(0.f, 0.f, 0.f, 0.f);
}

// ---------------- 1. histogram of top 11 bits of mapped score ----------------
__global__ __launch_bounds__(256) void hist_kernel(const float* __restrict__ obj,
                                                   int n, uint* __restrict__ hist) {
    __shared__ uint h[NBINS];
    for (int b = threadIdx.x; b < NBINS; b += 256) h[b] = 0;
    __syncthreads();
    int n4 = n >> 2;
    const float4* obj4 = reinterpret_cast<const float4*>(obj);
    int stride = gridDim.x * blockDim.x;
    for (int i = blockIdx.x * blockDim.x + threadIdx.x; i < n4; i += stride) {
        float4 v = obj4[i];
        atomicAdd(&h[map_f32(v.x) >> 21], 1u);
        atomicAdd(&h[map_f32(v.y) >> 21], 1u);
        atomicAdd(&h[map_f32(v.z) >> 21], 1u);
        atomicAdd(&h[map_f32(v.w) >> 21], 1u);
    }
    // tail
    int base = n4 << 2;
    for (int i = base + blockIdx.x * blockDim.x + threadIdx.x; i < n; i += stride)
        atomicAdd(&h[map_f32(obj[i]) >> 21], 1u);
    __syncthreads();
    for (int b = threadIdx.x; b < NBINS; b += 256)
        if (h[b]) atomicAdd(&hist[b], h[b]);
}

// ---------------- 2. find threshold bin (cum-from-top crosses PRE_NMS) -------
__global__ __launch_bounds__(256) void thresh_kernel(const uint* __restrict__ hist,
                                                     uint* __restrict__ meta) {
    __shared__ uint s_sum[256];
    __shared__ uint s_suf[256];
    int t = threadIdx.x;
    uint local[8];
    uint sum = 0;
#pragma unroll 8
    for (int b = 0; b < 8; b++) { local[b] = hist[t * 8 + b]; sum += local[b]; }
    s_sum[t] = sum;
    __syncthreads();
    if (t == 0) {
        uint acc = 0;
        for (int c = 255; c >= 0; c--) { s_suf[c] = acc; acc += s_sum[c]; }
    }
    __syncthreads();
    uint c = s_suf[t];  // count strictly above this chunk
#pragma unroll 8
    for (int b = 7; b >= 0; b--) {
        uint nc = c + local[b];
        if (c < (uint)PRE_NMS && nc >= (uint)PRE_NMS) meta[0] = (uint)(t * 8 + b);
        c = nc;
    }
}

// ---------------- 3. collect candidates >= threshold bin ---------------------
__global__ __launch_bounds__(256) void collect_kernel(const float* __restrict__ obj,
                                                      int n, uint* __restrict__ meta,
                                                      ull* __restrict__ cand) {
    uint T = meta[0];
    int n4 = n >> 2;
    const float4* obj4 = reinterpret_cast<const float4*>(obj);
    int stride = gridDim.x * blockDim.x;
    for (int i = blockIdx.x * blockDim.x + threadIdx.x; i < n4; i += stride) {
        float4 v = obj4[i];
        uint u0 = map_f32(v.x), u1 = map_f32(v.y), u2 = map_f32(v.z), u3 = map_f32(v.w);
        if ((u0 >> 21) >= T) {
            uint pos = atomicAdd(&meta[1], 1u);
            if (pos < (uint)SORT_N) cand[pos] = ((ull)u0 << 32) | (ull)(~(uint)(i * 4 + 0));
        }
        if ((u1 >> 21) >= T) {
            uint pos = atomicAdd(&meta[1], 1u);
            if (pos < (uint)SORT_N) cand[pos] = ((ull)u1 << 32) | (ull)(~(uint)(i * 4 + 1));
        }
        if ((u2 >> 21) >= T) {
            uint pos = atomicAdd(&meta[1], 1u);
            if (pos < (uint)SORT_N) cand[pos] = ((ull)u2 << 32) | (ull)(~(uint)(i * 4 + 2));
        }
        if ((u3 >> 21) >= T) {
            uint pos = atomicAdd(&meta[1], 1u);
            if (pos < (uint)SORT_N) cand[pos] = ((ull)u3 << 32) | (ull)(~(uint)(i * 4 + 3));
        }
    }
    int base = n4 << 2;
    for (int i = base + blockIdx.x * blockDim.x + threadIdx.x; i < n; i += stride) {
        uint u = map_f32(obj[i]);
        if ((u >> 21) >= T) {
            uint pos = atomicAdd(&meta[1], 1u);
            if (pos < (uint)SORT_N) cand[pos] = ((ull)u << 32) | (ull)(~(uint)i);
        }
    }
}

// ---------------- 4. bitonic sort (descending), emit top-2000 indices --------
__global__ __launch_bounds__(1024) void sort_kernel(const ull* __restrict__ cand,
                                                    const uint* __restrict__ meta,
                                                    int* __restrict__ topIdx) {
    __shared__ ull keys[SORT_N];
    uint n = meta[1]; if (n > (uint)SORT_N) n = SORT_N;
    for (int t = threadIdx.x; t < SORT_N; t += 1024)
        keys[t] = (t < (int)n) ? cand[t] : 0ULL;
    __syncthreads();
    for (int k = 2; k <= SORT_N; k <<= 1) {
        for (int j = k >> 1; j > 0; j >>= 1) {
            for (int t = threadIdx.x; t < SORT_N; t += 1024) {
                int ixj = t ^ j;
                if (ixj > t) {
                    ull A = keys[t], B = keys[ixj];
                    bool desc = ((t & k) == 0);
                    if (desc ? (A < B) : (A > B)) { keys[t] = B; keys[ixj] = A; }
                }
            }
            __syncthreads();
        }
    }
    for (int t = threadIdx.x; t < PRE_NMS; t += 1024)
        topIdx[t] = (int)(~(uint)keys[t]);   // low32 stored as ~idx
}

// ---------------- 5. gather + decode + clip + valid --------------------------
__global__ __launch_bounds__(256) void decode_kernel(const float* __restrict__ anchor,
                                                     const float* __restrict__ delta,
                                                     const int* __restrict__ topIdx,
                                                     const int* __restrict__ imh,
                                                     const int* __restrict__ imw,
                                                     float4* __restrict__ boxes,
                                                     ull* __restrict__ validWords) {
    int i = blockIdx.x * blockDim.x + threadIdx.x;
    if (i >= PRE_NMS) return;
    int idx = topIdx[i];
    const float4 a = reinterpret_cast<const float4*>(anchor)[idx];
    const float4 d = reinterpret_cast<const float4*>(delta)[idx];
    float W = (float)imw[0], H = (float)imh[0];
    float w  = a.z - a.x;
    float h  = a.w - a.y;
    float cx = a.x + 0.5f * w;
    float cy = a.y + 0.5f * h;
    float dw = fminf(d.z, BBOX_CLIP);
    float dh = fminf(d.w, BBOX_CLIP);
    float pcx = d.x * w + cx;
    float pcy = d.y * h + cy;
    float pw  = expf(dw) * w;
    float ph  = expf(dh) * h;
    float x1 = fminf(fmaxf(pcx - 0.5f * pw, 0.0f), W);
    float y1 = fminf(fmaxf(pcy - 0.5f * ph, 0.0f), H);
    float x2 = fminf(fmaxf(pcx + 0.5f * pw, 0.0f), W);
    float y2 = fminf(fmaxf(pcy + 0.5f * ph, 0.0f), H);
    boxes[i] = make_float4(x1, y1, x2, y2);
    bool valid = (x2 - x1 >= MIN_SIZE) && (y2 - y1 >= MIN_SIZE);
    if (valid) atomicOr(&validWords[i >> 6], 1ULL << (i & 63));
}

// ---------------- 6. suppression bitmatrix: mask[i][w] over j in [w*64, ...) -
__global__ __launch_bounds__(256) void mask_kernel(const float4* __restrict__ boxes,
                                                   ull* __restrict__ mask) {
    __shared__ float4 b[PRE_NMS];
    for (int t = threadIdx.x; t < PRE_NMS; t += 256) b[t] = boxes[t];
    __syncthreads();
    int tid = blockIdx.x * 256 + threadIdx.x;
    int i = tid >> 5, w = tid & 31;
    if (i >= PRE_NMS) return;
    float4 bi = b[i];
    float areai = (bi.z - bi.x) * (bi.w - bi.y);
    ull m = 0;
    int j0 = w * 64;
    for (int jj = 0; jj < 64; jj++) {
        int j = j0 + jj;
        if (j < PRE_NMS && j > i) {
            float4 bj = b[j];
            float xx1 = fmaxf(bi.x, bj.x), yy1 = fmaxf(bi.y, bj.y);
            float xx2 = fminf(bi.z, bj.z), yy2 = fminf(bi.w, bj.w);
            float inter = fmaxf(xx2 - xx1, 0.0f) * fmaxf(yy2 - yy1, 0.0f);
            float areaj = (bj.z - bj.x) * (bj.w - bj.y);
            float iou = inter / (areai + areaj - inter + 1e-9f);
            if (iou > NMS_TH) m |= (1ULL << jj);
        }
    }
    mask[i * 32 + w] = m;
}

// ---------------- 7. blocked serial greedy NMS (1 wave, LDS double-buffer) ---
// Block w = rows [64w, 64w+64) = rem word w. Serial chain is pure VALU on a
// replicated remw register. Mask blocks (16 KB) staged ahead into LDS via
// 16x global_load_lds(width=16); counted s_waitcnt vmcnt(16) keeps the next
// block's loads in flight (never drain to 0 mid-loop).
__device__ __forceinline__ void nms_stage_block(const char* mb, ull* dst,
                                                int w, int lane) {
    const size_t base = (size_t)w * 16384;   // 64 rows * 256 B
#pragma unroll
    for (int k = 0; k < 16; ++k) {
        size_t off = base + (size_t)k * 1024;
        // clamp chunks past the real 2000 rows (block 31) to mask base;
        // garbage lands in LDS rows >= nrow which are never read.
        const char* src = (off + 1024 <= (size_t)PRE_NMS * 256) ? (mb + off) : mb;
        __builtin_amdgcn_global_load_lds(
            (const __attribute__((address_space(1))) uint*)(src + lane * 16),
            (__attribute__((address_space(3))) uint*)((char*)dst + k * 1024),
            16, 0, 0);
    }
}

__global__ __launch_bounds__(64) void nms_kernel(const ull* __restrict__ mask,
                                                 const ull* __restrict__ validWords,
                                                 ull* __restrict__ remOut) {
    __shared__ ull buf[2][2048];   // 2 x (64 rows x 32 words) = 32 KB
    const int lane = threadIdx.x;
    ull rem = (lane < 32) ? ~validWords[lane] : ~0ULL;   // removed = !valid
    const char* mb = (const char*)mask;

    nms_stage_block(mb, &buf[0][0], 0, lane);            // prologue: block 0

    for (int w = 0; w < 32; ++w) {
        const int b = w & 1;
        if (w + 1 < 32) {
            nms_stage_block(mb, &buf[b ^ 1][0], w + 1, lane);
            asm volatile("s_waitcnt vmcnt(16)" ::: "memory");  // drain block w only
        } else {
            asm volatile("s_waitcnt vmcnt(0)" ::: "memory");
        }
        __builtin_amdgcn_sched_barrier(0);

        ull remw = __shfl(rem, w);            // this block's suppression word
        const int nrow = PRE_NMS - w * 64 < 64 ? PRE_NMS - w * 64 : 64;
        const int lw = lane & 31;
#pragma unroll
        for (int i = 0; i < 64; ++i) {
            ull d = buf[b][i * 32 + w];       // broadcast: row's intra-block word
            ull o = buf[b][i * 32 + lw];      // per-lane: row's word for rem
            bool act = (i < nrow) && !((remw >> i) & 1ULL);
            ull sel = act ? ~0ULL : 0ULL;
            remw |= d & sel;
            rem  |= o & sel;
        }
    }
    if (lane < 32) remOut[lane] = rem;
}

// ---------------- 8. scatter kept boxes in positional (score) order ----------
__global__ __launch_bounds__(256) void output_kernel(const float4* __restrict__ boxes,
                                                     const ull* __restrict__ rem,
                                                     float4* __restrict__ out) {
    __shared__ uint pre[33];
    __shared__ ull kept_s[32];
    int t = threadIdx.x;
    if (t < 32) kept_s[t] = ~rem[t];
    __syncthreads();
    if (t == 0) {
        uint acc = 0;
        for (int w = 0; w < 32; w++) { pre[w] = acc; acc += (uint)__popcll(kept_s[w]); }
        pre[32] = acc;
    }
    __syncthreads();
    for (int i = t; i < PRE_NMS; i += 256) {
        ull kw = kept_s[i >> 6];
        if ((kw >> (i & 63)) & 1ULL) {
            uint rank = pre[i >> 6] +
                        (uint)__popcll(kw & ((1ULL << (i & 63)) - 1ULL));
            if (rank < (uint)POST_NMS) out[rank] = boxes[i];
        }
    }
}

extern "C" void kernel_launch(void* const* d_in, const int* in_sizes, int n_in,
                              void* d_out, int out_size, void* d_ws, size_t ws_size,
                              hipStream_t stream) {
    const float* anchor = (const float*)d_in[0];
    const float* obj    = (const float*)d_in[1];
    const float* delta  = (const float*)d_in[2];
    const int*   imh    = (const int*)d_in[3];
    const int*   imw    = (const int*)d_in[4];
    int n = in_sizes[1];

    char* ws = (char*)d_ws;
    uint* hist       = (uint*)(ws + HIST_OFF);
    uint* meta       = (uint*)(ws + META_OFF);
    ull*  validWords = (ull*)(ws + VALID_OFF);
    ull*  cand       = (ull*)(ws + CAND_OFF);
    int*  topIdx     = (int*)(ws + TOPIDX_OFF);
    float4* boxes    = (float4*)(ws + BOXES_OFF);
    ull*  mask       = (ull*)(ws + MASK_OFF);
    ull*  rem        = (ull*)(ws + REM_OFF);

    init_kernel<<<(ZERO_WORDS + 255) / 256, 256, 0, stream>>>(
        (uint*)ws, (float4*)d_out);
    hist_kernel<<<512, 256, 0, stream>>>(obj, n, hist);
    thresh_kernel<<<1, 256, 0, stream>>>(hist, meta);
    collect_kernel<<<512, 256, 0, stream>>>(obj, n, meta, cand);
    sort_kernel<<<1, 1024, 0, stream>>>(cand, meta, topIdx);
    decode_kernel<<<(PRE_NMS + 255) / 256, 256, 0, stream>>>(
        anchor, delta, topIdx, imh, imw, boxes, validWords);
    mask_kernel<<<(PRE_NMS * 32 + 255) / 256, 256, 0, stream>>>(boxes, mask);
    nms_kernel<<<1, 64, 0, stream>>>(mask, validWords, rem);
    output_kernel<<<1, 256, 0, stream>>>(boxes, rem, (float4*)d_out);
}

// Round 9
// 290.024 us; speedup vs baseline: 1.8750x; 1.0941x over previous
//
#include <hip/hip_runtime.h>
#include <hip/hip_bf16.h>

// RPN proposal: top-2000 -> decode/clip -> greedy NMS -> top-1000 proposals.
// Pipeline: init -> hist(2048 bins) -> threshold -> collect -> bitonic sort ->
//           decode -> IoU bitmask matrix (COLUMN-MAJOR) -> blocked serial NMS
//           (register-pipelined) -> scatter out.
//
// R9: nms rebuilt again. R8 measured 87.6us: VALUBusy~0 => wave stalled on
// un-pipelined ds_read latency (~103 cyc/iter ~= single-outstanding ds_read),
// and 16KB staged per block while only 2 columns (1KB) were consumed.
// Now: mask stored column-major; block w stages 32 contiguous 512B column
// slices (global_load_lds w=16, pre-swizzled source u=q^(c&15) so strided
// column reads are 2-way bank-free); serial chain is pure VALU with a manual
// 4x16-row register pipeline (dA/oA compute || dB/oB ds_read_b128 prefetch).

typedef unsigned int uint;
typedef unsigned long long ull;

#define PRE_NMS   2000
#define POST_NMS  1000
#define SORT_N    4096
#define NBINS     2048
#define NMS_TH    0.7f
#define MIN_SIZE  1.0f
#define BBOX_CLIP 4.135166556742356f   // float(ln(1000/16))

#define CM_ROWS   2048                 // padded rows per mask column

// ---- ws layout (bytes) ----
#define HIST_OFF    0        // 2048 * 4 = 8192
#define META_OFF    8192     // 64 uints (meta[0]=threshold bin, meta[1]=cand count)
#define VALID_OFF   8448     // 32 * 8 = 256
#define CAND_OFF    8704     // 4096 * 8 = 32768
#define TOPIDX_OFF  41472    // 2000 * 4 = 8000
#define BOXES_OFF   49472    // 2000 * 16 = 32000 (16B aligned)
#define MASK_OFF    81472    // 32 cols * 2048 rows * 8 = 524288
#define REM_OFF     605760   // 32 * 8 = 256
#define ZERO_WORDS  2176     // (hist + meta + validWords) / 4 = 8704 B

__device__ __forceinline__ uint map_f32(float f) {
    uint u = __float_as_uint(f);
    return u ^ ((u & 0x80000000u) ? 0xFFFFFFFFu : 0x80000000u);
}

// ---------------- 0. zero ws header + output --------------------------------
__global__ __launch_bounds__(256) void init_kernel(uint* __restrict__ wsHead,
                                                   float4* __restrict__ out) {
    int t = blockIdx.x * 256 + threadIdx.x;
    if (t < ZERO_WORDS) wsHead[t] = 0u;
    if (t < POST_NMS) out[t] = make_float4(0.f, 0.f, 0.f, 0.f);
}

// ---------------- 1. histogram of top 11 bits of mapped score ----------------
__global__ __launch_bounds__(256) void hist_kernel(const float* __restrict__ obj,
                                                   int n, uint* __restrict__ hist) {
    __shared__ uint h[NBINS];
    for (int b = threadIdx.x; b < NBINS; b += 256) h[b] = 0;
    __syncthreads();
    int n4 = n >> 2;
    const float4* obj4 = reinterpret_cast<const float4*>(obj);
    int stride = gridDim.x * blockDim.x;
    for (int i = blockIdx.x * blockDim.x + threadIdx.x; i < n4; i += stride) {
        float4 v = obj4[i];
        atomicAdd(&h[map_f32(v.x) >> 21], 1u);
        atomicAdd(&h[map_f32(v.y) >> 21], 1u);
        atomicAdd(&h[map_f32(v.z) >> 21], 1u);
        atomicAdd(&h[map_f32(v.w) >> 21], 1u);
    }
    int base = n4 << 2;
    for (int i = base + blockIdx.x * blockDim.x + threadIdx.x; i < n; i += stride)
        atomicAdd(&h[map_f32(obj[i]) >> 21], 1u);
    __syncthreads();
    for (int b = threadIdx.x; b < NBINS; b += 256)
        if (h[b]) atomicAdd(&hist[b], h[b]);
}

// ---------------- 2. find threshold bin (cum-from-top crosses PRE_NMS) -------
__global__ __launch_bounds__(256) void thresh_kernel(const uint* __restrict__ hist,
                                                     uint* __restrict__ meta) {
    __shared__ uint s_sum[256];
    __shared__ uint s_suf[256];
    int t = threadIdx.x;
    uint local[8];
    uint sum = 0;
#pragma unroll 8
    for (int b = 0; b < 8; b++) { local[b] = hist[t * 8 + b]; sum += local[b]; }
    s_sum[t] = sum;
    __syncthreads();
    if (t == 0) {
        uint acc = 0;
        for (int c = 255; c >= 0; c--) { s_suf[c] = acc; acc += s_sum[c]; }
    }
    __syncthreads();
    uint c = s_suf[t];  // count strictly above this chunk
#pragma unroll 8
    for (int b = 7; b >= 0; b--) {
        uint nc = c + local[b];
        if (c < (uint)PRE_NMS && nc >= (uint)PRE_NMS) meta[0] = (uint)(t * 8 + b);
        c = nc;
    }
}

// ---------------- 3. collect candidates >= threshold bin ---------------------
__global__ __launch_bounds__(256) void collect_kernel(const float* __restrict__ obj,
                                                      int n, uint* __restrict__ meta,
                                                      ull* __restrict__ cand) {
    uint T = meta[0];
    int n4 = n >> 2;
    const float4* obj4 = reinterpret_cast<const float4*>(obj);
    int stride = gridDim.x * blockDim.x;
    for (int i = blockIdx.x * blockDim.x + threadIdx.x; i < n4; i += stride) {
        float4 v = obj4[i];
        uint u0 = map_f32(v.x), u1 = map_f32(v.y), u2 = map_f32(v.z), u3 = map_f32(v.w);
        if ((u0 >> 21) >= T) {
            uint pos = atomicAdd(&meta[1], 1u);
            if (pos < (uint)SORT_N) cand[pos] = ((ull)u0 << 32) | (ull)(~(uint)(i * 4 + 0));
        }
        if ((u1 >> 21) >= T) {
            uint pos = atomicAdd(&meta[1], 1u);
            if (pos < (uint)SORT_N) cand[pos] = ((ull)u1 << 32) | (ull)(~(uint)(i * 4 + 1));
        }
        if ((u2 >> 21) >= T) {
            uint pos = atomicAdd(&meta[1], 1u);
            if (pos < (uint)SORT_N) cand[pos] = ((ull)u2 << 32) | (ull)(~(uint)(i * 4 + 2));
        }
        if ((u3 >> 21) >= T) {
            uint pos = atomicAdd(&meta[1], 1u);
            if (pos < (uint)SORT_N) cand[pos] = ((ull)u3 << 32) | (ull)(~(uint)(i * 4 + 3));
        }
    }
    int base = n4 << 2;
    for (int i = base + blockIdx.x * blockDim.x + threadIdx.x; i < n; i += stride) {
        uint u = map_f32(obj[i]);
        if ((u >> 21) >= T) {
            uint pos = atomicAdd(&meta[1], 1u);
            if (pos < (uint)SORT_N) cand[pos] = ((ull)u << 32) | (ull)(~(uint)i);
        }
    }
}

// ---------------- 4. bitonic sort (descending), emit top-2000 indices --------
__global__ __launch_bounds__(1024) void sort_kernel(const ull* __restrict__ cand,
                                                    const uint* __restrict__ meta,
                                                    int* __restrict__ topIdx) {
    __shared__ ull keys[SORT_N];
    uint n = meta[1]; if (n > (uint)SORT_N) n = SORT_N;
    for (int t = threadIdx.x; t < SORT_N; t += 1024)
        keys[t] = (t < (int)n) ? cand[t] : 0ULL;
    __syncthreads();
    for (int k = 2; k <= SORT_N; k <<= 1) {
        for (int j = k >> 1; j > 0; j >>= 1) {
            for (int t = threadIdx.x; t < SORT_N; t += 1024) {
                int ixj = t ^ j;
                if (ixj > t) {
                    ull A = keys[t], B = keys[ixj];
                    bool desc = ((t & k) == 0);
                    if (desc ? (A < B) : (A > B)) { keys[t] = B; keys[ixj] = A; }
                }
            }
            __syncthreads();
        }
    }
    for (int t = threadIdx.x; t < PRE_NMS; t += 1024)
        topIdx[t] = (int)(~(uint)keys[t]);   // low32 stored as ~idx
}

// ---------------- 5. gather + decode + clip + valid --------------------------
__global__ __launch_bounds__(256) void decode_kernel(const float* __restrict__ anchor,
                                                     const float* __restrict__ delta,
                                                     const int* __restrict__ topIdx,
                                                     const int* __restrict__ imh,
                                                     const int* __restrict__ imw,
                                                     float4* __restrict__ boxes,
                                                     ull* __restrict__ validWords) {
    int i = blockIdx.x * blockDim.x + threadIdx.x;
    if (i >= PRE_NMS) return;
    int idx = topIdx[i];
    const float4 a = reinterpret_cast<const float4*>(anchor)[idx];
    const float4 d = reinterpret_cast<const float4*>(delta)[idx];
    float W = (float)imw[0], H = (float)imh[0];
    float w  = a.z - a.x;
    float h  = a.w - a.y;
    float cx = a.x + 0.5f * w;
    float cy = a.y + 0.5f * h;
    float dw = fminf(d.z, BBOX_CLIP);
    float dh = fminf(d.w, BBOX_CLIP);
    float pcx = d.x * w + cx;
    float pcy = d.y * h + cy;
    float pw  = expf(dw) * w;
    float ph  = expf(dh) * h;
    float x1 = fminf(fmaxf(pcx - 0.5f * pw, 0.0f), W);
    float y1 = fminf(fmaxf(pcy - 0.5f * ph, 0.0f), H);
    float x2 = fminf(fmaxf(pcx + 0.5f * pw, 0.0f), W);
    float y2 = fminf(fmaxf(pcy + 0.5f * ph, 0.0f), H);
    boxes[i] = make_float4(x1, y1, x2, y2);
    bool valid = (x2 - x1 >= MIN_SIZE) && (y2 - y1 >= MIN_SIZE);
    if (valid) atomicOr(&validWords[i >> 6], 1ULL << (i & 63));
}

// ---------------- 6. suppression bitmatrix, COLUMN-MAJOR ---------------------
// maskCM[c * CM_ROWS + r] = word c of row r (bits for rows 64c..64c+63 that
// row r suppresses). 64 consecutive tids share word c, vary row => coalesced.
__global__ __launch_bounds__(256) void mask_kernel(const float4* __restrict__ boxes,
                                                   ull* __restrict__ maskCM) {
    __shared__ float4 b[PRE_NMS];
    for (int t = threadIdx.x; t < PRE_NMS; t += 256) b[t] = boxes[t];
    __syncthreads();
    int tid = blockIdx.x * 256 + threadIdx.x;   // 0 .. 32*2048-1
    int c = tid >> 11;          // word 0..31
    int r = tid & (CM_ROWS - 1);
    ull m = 0;
    if (r < PRE_NMS) {
        float4 bi = b[r];
        float areai = (bi.z - bi.x) * (bi.w - bi.y);
        int j0 = c * 64;
#pragma unroll
        for (int jj = 0; jj < 64; jj++) {
            int j = j0 + jj;
            if (j < PRE_NMS && j > r) {
                float4 bj = b[j];
                float xx1 = fmaxf(bi.x, bj.x), yy1 = fmaxf(bi.y, bj.y);
                float xx2 = fminf(bi.z, bj.z), yy2 = fminf(bi.w, bj.w);
                float inter = fmaxf(xx2 - xx1, 0.0f) * fmaxf(yy2 - yy1, 0.0f);
                float areaj = (bj.z - bj.x) * (bj.w - bj.y);
                float iou = inter / (areai + areaj - inter + 1e-9f);
                if (iou > NMS_TH) m |= (1ULL << jj);
            }
        }
    }
    maskCM[tid] = m;
}

// ---------------- 7. blocked serial greedy NMS (1 wave, reg-pipelined) -------
// Block w = rows [64w,64w+64). LDS holds 32 column slices (512 B each) of the
// block, staged by global_load_lds with pre-swizzled SOURCE (u = q ^ (c&15))
// so the strided column reads are 2-way bank-aliased (free). Serial chain is
// pure VALU on replicated remw; ds_read_b128s run 1 chunk (16 rows) ahead.
__device__ __forceinline__ void nms_stage_block(const char* mb, void* dst,
                                                int w, int lane) {
    const int c0 = lane >> 5;        // 0 or 1
    const int u  = lane & 31;        // 16B unit within column slice
#pragma unroll
    for (int k = 0; k < 16; ++k) {
        const int c = 2 * k + c0;                     // column 0..31
        const int q = u ^ (c & 15);                   // inverse swizzle
        const char* src = mb + (size_t)c * (CM_ROWS * 8)
                             + (size_t)w * 512 + (size_t)(q * 16);
        __builtin_amdgcn_global_load_lds(
            (const __attribute__((address_space(1))) uint*)src,
            (__attribute__((address_space(3))) uint*)((char*)dst + k * 1024),
            16, 0, 0);
    }
}

__global__ __launch_bounds__(64) void nms_kernel(const ull* __restrict__ maskCM,
                                                 const ull* __restrict__ validWords,
                                                 ull* __restrict__ remOut) {
    __shared__ __align__(16) ull buf[2][2048];   // 2 x 32 cols x 64 rows = 32 KB
    const int lane = threadIdx.x;
    const int lw = lane & 31;
    ull rem = (lane < 32) ? ~validWords[lane] : ~0ULL;   // removed = !valid
    const char* mb = (const char*)maskCM;

    nms_stage_block(mb, &buf[0][0], 0, lane);            // prologue: block 0

    for (int w = 0; w < 32; ++w) {
        const int b = w & 1;
        if (w + 1 < 32) {
            nms_stage_block(mb, &buf[b ^ 1][0], w + 1, lane);
            asm volatile("s_waitcnt vmcnt(16)" ::: "memory");  // block w landed
        } else {
            asm volatile("s_waitcnt vmcnt(0)" ::: "memory");
        }
        __builtin_amdgcn_sched_barrier(0);

        ull remw = __shfl(rem, w);        // this block's suppression word
        const char* ldsb = (const char*)&buf[b][0];
        const char* dcol = ldsb + 512 * w;     // intra-block word column
        const char* ocol = ldsb + 512 * lw;    // this lane's rem-word column
        const int sw = (w & 15) << 4;          // read swizzle (matches source)
        const int so = (lw & 15) << 4;

        ulonglong2 dA[8], oA[8], dB[8], oB[8];
#pragma unroll
        for (int q = 0; q < 8; ++q) {
            dA[q] = *(const ulonglong2*)(dcol + ((q << 4) ^ sw));
            oA[q] = *(const ulonglong2*)(ocol + ((q << 4) ^ so));
        }
#pragma unroll
        for (int ch = 0; ch < 4; ++ch) {
            if (ch < 3) {                      // prefetch next 16 rows
#pragma unroll
                for (int q = 0; q < 8; ++q) {
                    const int qg = (ch + 1) * 8 + q;
                    dB[q] = *(const ulonglong2*)(dcol + ((qg << 4) ^ sw));
                    oB[q] = *(const ulonglong2*)(ocol + ((qg << 4) ^ so));
                }
            }
#pragma unroll
            for (int t = 0; t < 16; ++t) {     // serial chain: pure VALU
                const int i = ch * 16 + t;
                ull d = (t & 1) ? dA[t >> 1].y : dA[t >> 1].x;
                ull o = (t & 1) ? oA[t >> 1].y : oA[t >> 1].x;
                ull bit = (remw >> i) & 1ULL;
                ull sel = bit - 1ULL;          // 0 -> all-ones, 1 -> zero
                remw |= d & sel;
                rem  |= o & sel;
            }
#pragma unroll
            for (int q = 0; q < 8; ++q) { dA[q] = dB[q]; oA[q] = oB[q]; }
        }
    }
    if (lane < 32) remOut[lane] = rem;
}

// ---------------- 8. scatter kept boxes in positional (score) order ----------
__global__ __launch_bounds__(256) void output_kernel(const float4* __restrict__ boxes,
                                                     const ull* __restrict__ rem,
                                                     float4* __restrict__ out) {
    __shared__ uint pre[33];
    __shared__ ull kept_s[32];
    int t = threadIdx.x;
    if (t < 32) kept_s[t] = ~rem[t];
    __syncthreads();
    if (t == 0) {
        uint acc = 0;
        for (int w = 0; w < 32; w++) { pre[w] = acc; acc += (uint)__popcll(kept_s[w]); }
        pre[32] = acc;
    }
    __syncthreads();
    for (int i = t; i < PRE_NMS; i += 256) {
        ull kw = kept_s[i >> 6];
        if ((kw >> (i & 63)) & 1ULL) {
            uint rank = pre[i >> 6] +
                        (uint)__popcll(kw & ((1ULL << (i & 63)) - 1ULL));
            if (rank < (uint)POST_NMS) out[rank] = boxes[i];
        }
    }
}

extern "C" void kernel_launch(void* const* d_in, const int* in_sizes, int n_in,
                              void* d_out, int out_size, void* d_ws, size_t ws_size,
                              hipStream_t stream) {
    const float* anchor = (const float*)d_in[0];
    const float* obj    = (const float*)d_in[1];
    const float* delta  = (const float*)d_in[2];
    const int*   imh    = (const int*)d_in[3];
    const int*   imw    = (const int*)d_in[4];
    int n = in_sizes[1];

    char* ws = (char*)d_ws;
    uint* hist       = (uint*)(ws + HIST_OFF);
    uint* meta       = (uint*)(ws + META_OFF);
    ull*  validWords = (ull*)(ws + VALID_OFF);
    ull*  cand       = (ull*)(ws + CAND_OFF);
    int*  topIdx     = (int*)(ws + TOPIDX_OFF);
    float4* boxes    = (float4*)(ws + BOXES_OFF);
    ull*  maskCM     = (ull*)(ws + MASK_OFF);
    ull*  rem        = (ull*)(ws + REM_OFF);

    init_kernel<<<(ZERO_WORDS + 255) / 256, 256, 0, stream>>>(
        (uint*)ws, (float4*)d_out);
    hist_kernel<<<512, 256, 0, stream>>>(obj, n, hist);
    thresh_kernel<<<1, 256, 0, stream>>>(hist, meta);
    collect_kernel<<<512, 256, 0, stream>>>(obj, n, meta, cand);
    sort_kernel<<<1, 1024, 0, stream>>>(cand, meta, topIdx);
    decode_kernel<<<(PRE_NMS + 255) / 256, 256, 0, stream>>>(
        anchor, delta, topIdx, imh, imw, boxes, validWords);
    mask_kernel<<<(32 * CM_ROWS) / 256, 256, 0, stream>>>(boxes, maskCM);
    nms_kernel<<<1, 64, 0, stream>>>(maskCM, validWords, rem);
    output_kernel<<<1, 256, 0, stream>>>(boxes, rem, (float4*)d_out);
}